// Round 5
// baseline (282.668 us; speedup 1.0000x reference)
//
#include <hip/hip_runtime.h>

typedef unsigned short u16;
typedef __bf16 bf16x8 __attribute__((ext_vector_type(8)));
typedef float floatx4 __attribute__((ext_vector_type(4)));

#define B_ 4
#define SEQ 2048
#define DIM 1024

__device__ __forceinline__ u16 f2bf(float f) {
    unsigned u = __builtin_bit_cast(unsigned, f);
    u += 0x7FFFu + ((u >> 16) & 1u);
    return (u16)(u >> 16);
}
__device__ __forceinline__ float bf2f(u16 h) {
    unsigned u = ((unsigned)h) << 16;
    return __builtin_bit_cast(float, u);
}

#define GPTR(p) ((const __attribute__((address_space(1))) void*)(p))
#define LPTR(p) ((__attribute__((address_space(3))) void*)(p))

// ---------------- convert x fp32 -> bf16 ----------------
__global__ __launch_bounds__(256) void convert_x(const float4* __restrict__ x,
                                                 ushort4* __restrict__ xb) {
    int i = blockIdx.x * 256 + threadIdx.x;  // 2M float4s
    float4 v = x[i];
    ushort4 o;
    o.x = f2bf(v.x); o.y = f2bf(v.y); o.z = f2bf(v.z); o.w = f2bf(v.w);
    xb[i] = o;
}

// ---------------- transpose W [k][n] fp32 -> Wt [n][k] bf16 ----------------
__global__ __launch_bounds__(256) void transpose_w(const float* __restrict__ Wq,
                                                   const float* __restrict__ Wk,
                                                   const float* __restrict__ Wv,
                                                   u16* __restrict__ Wt) {
    __shared__ u16 t[64][66];
    const int z = blockIdx.z;
    const float* W = (z == 0) ? Wq : ((z == 1) ? Wk : Wv);
    u16* out = Wt + (size_t)z * DIM * DIM;
    const int tx = threadIdx.x, ty = threadIdx.y;  // (32,8)
    const int k0 = blockIdx.x * 64, n0 = blockIdx.y * 64;
#pragma unroll
    for (int j = 0; j < 8; j++) {
        int k = ty + 8 * j;
        float2 v = *(const float2*)(W + (size_t)(k0 + k) * DIM + n0 + 2 * tx);
        t[2 * tx][k] = f2bf(v.x);
        t[2 * tx + 1][k] = f2bf(v.y);
    }
    __syncthreads();
#pragma unroll
    for (int j = 0; j < 8; j++) {
        int n = ty + 8 * j;
        ushort2 o;
        o.x = t[n][2 * tx];
        o.y = t[n][2 * tx + 1];
        *(ushort2*)(out + (size_t)(n0 + n) * DIM + k0 + 2 * tx) = o;
    }
}

// ---- 128x64 bf16 MFMA mainloop, BK=64 as two 32-col panels -----------------
// A [m][k] row-major, B transposed [n][k]. 4 waves in 2x2; wave = 64mx32n.
// acc = 4x2 frags (32 AGPR). LDS: lsA 128*64 u16 (16 KB), lsB 64*64 (8 KB).
__device__ __forceinline__ void mainloop(
    const u16* __restrict__ Ab, const u16* __restrict__ Bb, int lda, int ldb,
    int Kt, u16* lsA, u16* lsB, int tid, int wave, int quad, int l15,
    int wm, int wn, floatx4 (&acc)[4][2]) {
    const int srow = tid >> 2;         // 0..63
    const int scol = (tid & 3) * 8;
    const u16* gA = Ab + (size_t)srow * lda + scol;
    const u16* gB = Bb + (size_t)srow * ldb + scol;

#pragma unroll
    for (int i = 0; i < 4; i++)
#pragma unroll
        for (int j = 0; j < 2; j++) {
            floatx4 zz = {0.f, 0.f, 0.f, 0.f};
            acc[i][j] = zz;
        }

    for (int k0 = 0; k0 < Kt; k0 += 64) {
#pragma unroll
        for (int h = 0; h < 2; h++) {
            __builtin_amdgcn_global_load_lds(GPTR(gA + h * 32),
                LPTR(lsA + h * 4096 + wave * 512), 16, 0, 0);
            __builtin_amdgcn_global_load_lds(GPTR(gA + (size_t)64 * lda + h * 32),
                LPTR(lsA + h * 4096 + 2048 + wave * 512), 16, 0, 0);
            __builtin_amdgcn_global_load_lds(GPTR(gB + h * 32),
                LPTR(lsB + h * 2048 + wave * 512), 16, 0, 0);
        }
        gA += 64; gB += 64;
        __syncthreads();

#pragma unroll
        for (int h = 0; h < 2; h++) {
            bf16x8 af[4], bfr[2];
#pragma unroll
            for (int i = 0; i < 4; i++)
                af[i] = *(const bf16x8*)(lsA + h * 4096 + (wm + i * 16 + l15) * 32 + quad * 8);
#pragma unroll
            for (int j = 0; j < 2; j++)
                bfr[j] = *(const bf16x8*)(lsB + h * 2048 + (wn + j * 16 + l15) * 32 + quad * 8);
#pragma unroll
            for (int i = 0; i < 4; i++)
#pragma unroll
                for (int j = 0; j < 2; j++)
                    acc[i][j] = __builtin_amdgcn_mfma_f32_16x16x32_bf16(af[i], bfr[j], acc[i][j], 0, 0, 0);
        }
        __syncthreads();
    }
}

// ---------------- QKV projection: C = xb @ Wt^T + bias ----------------------
// grid (48,64): z = x>>4 (Q,K,V), 64-col tile = x&15. x-adjacent share A-tile.
__global__ __launch_bounds__(256, 4) void gemm_qkv(
    const u16* __restrict__ A, const u16* __restrict__ Bt, u16* __restrict__ QK,
    const float* __restrict__ b0, const float* __restrict__ b1, const float* __restrict__ b2,
    u16* __restrict__ VtOut) {
    __shared__ union {
        struct { u16 a[128 * 64]; u16 b[64 * 64]; } stage;  // 24 KB
        u16 epT[64 * 136];       // V^T epilogue staging (17.4 KB)
    } sm;
    const int tid = threadIdx.x;
    const int wave = tid >> 6, lane = tid & 63;
    const int quad = lane >> 4, l15 = lane & 15;
    const int wm = (wave >> 1) * 64, wn = (wave & 1) * 32;
    const int z = blockIdx.x >> 4, xn = blockIdx.x & 15, yb = blockIdx.y;

    const u16* Ab = A + (size_t)yb * 128 * DIM;
    const u16* Bb = Bt + (size_t)z * DIM * DIM + (size_t)xn * 64 * DIM;
    floatx4 acc[4][2];
    mainloop(Ab, Bb, DIM, DIM, DIM, sm.stage.a, sm.stage.b,
             tid, wave, quad, l15, wm, wn, acc);

    const int colbase = xn * 64;
    const int mq = quad * 4;
    const float* bias = (z == 0) ? b0 : ((z == 1) ? b1 : b2);
    const int n0 = colbase + wn + l15;

    if (z < 2) {
        u16* Cb = QK + (size_t)z * B_ * SEQ * DIM;
        const int m0 = yb * 128 + wm + mq;
#pragma unroll
        for (int j = 0; j < 2; j++) {
            float bv_ = bias[n0 + j * 16];
#pragma unroll
            for (int i = 0; i < 4; i++)
#pragma unroll
                for (int r = 0; r < 4; r++)
                    Cb[(size_t)(m0 + i * 16 + r) * DIM + (n0 + j * 16)] = f2bf(acc[i][j][r] + bv_);
        }
        return;
    }

    // z == 2: write V^T [d][s] per batch via LDS transpose staging (one pass)
    float addj[2];
#pragma unroll
    for (int j = 0; j < 2; j++) addj[j] = bias[n0 + j * 16];
    __syncthreads();
#pragma unroll
    for (int i = 0; i < 4; i++)
#pragma unroll
        for (int j = 0; j < 2; j++)
#pragma unroll
            for (int r = 0; r < 4; r++) {
                int lr = wm + i * 16 + mq + r;   // local row 0..127 (token)
                int lc = wn + j * 16 + l15;      // local col 0..63  (dim)
                sm.epT[lc * 136 + lr] = f2bf(acc[i][j][r] + addj[j]);
            }
    __syncthreads();
    const int b = (yb * 128) >> 11;
    const int sb = (yb * 128) & (SEQ - 1);
    u16* Vb = VtOut + (size_t)b * DIM * SEQ;
#pragma unroll
    for (int k = 0; k < 4; k++) {
        int s2 = tid + 256 * k;        // 0..1023
        int n = s2 >> 4, seg = s2 & 15;
        uint4 val = *(const uint4*)&sm.epT[n * 136 + seg * 8];
        *(uint4*)(Vb + (size_t)(colbase + n) * SEQ + sb + seg * 8) = val;
    }
}

// ------- scores: S = Q @ K^T * scale (128x64, causal, heavy-first) ----------
__global__ __launch_bounds__(256, 4) void gemm_scores(
    const u16* __restrict__ Q, const u16* __restrict__ K, u16* __restrict__ S,
    float scale) {
    const int ym = gridDim.y - 1 - blockIdx.y;   // 0..15, heavy-first
    if ((int)blockIdx.x > 2 * ym + 1) return;    // fully-masked 64-col tile

    __shared__ u16 lsA[128 * 64];   // 16 KB
    __shared__ u16 lsB[64 * 64];    // 8 KB
    const int tid = threadIdx.x;
    const int wave = tid >> 6, lane = tid & 63;
    const int quad = lane >> 4, l15 = lane & 15;
    const int wm = (wave >> 1) * 64, wn = (wave & 1) * 32;
    const int z = blockIdx.z;

    const u16* Ab = Q + (size_t)z * SEQ * DIM + (size_t)ym * 128 * DIM;
    const u16* Bb = K + (size_t)z * SEQ * DIM + (size_t)blockIdx.x * 64 * DIM;
    floatx4 acc[4][2];
    mainloop(Ab, Bb, DIM, DIM, DIM, lsA, lsB,
             tid, wave, quad, l15, wm, wn, acc);

    u16* Cb = S + (size_t)z * SEQ * SEQ;
    const int m0 = ym * 128 + wm + quad * 4;
    const int n0 = blockIdx.x * 64 + wn + l15;
#pragma unroll
    for (int j = 0; j < 2; j++)
#pragma unroll
        for (int i = 0; i < 4; i++)
#pragma unroll
            for (int r = 0; r < 4; r++)
                Cb[(size_t)(m0 + i * 16 + r) * SEQ + (n0 + j * 16)] = f2bf(acc[i][j][r] * scale);
}

// ------- context: out = P @ Vt^T (128x64, K limited, heavy-first) -----------
__global__ __launch_bounds__(256, 4) void gemm_pv(
    const u16* __restrict__ P, const u16* __restrict__ Vt, float* __restrict__ O) {
    const int ym = gridDim.y - 1 - blockIdx.y;   // 0..15, heavy-first
    __shared__ u16 lsA[128 * 64];
    __shared__ u16 lsB[64 * 64];
    const int tid = threadIdx.x;
    const int wave = tid >> 6, lane = tid & 63;
    const int quad = lane >> 4, l15 = lane & 15;
    const int wm = (wave >> 1) * 64, wn = (wave & 1) * 32;
    const int z = blockIdx.z;

    const u16* Ab = P + (size_t)z * SEQ * SEQ + (size_t)ym * 128 * SEQ;
    const u16* Bb = Vt + (size_t)z * DIM * SEQ + (size_t)blockIdx.x * 64 * SEQ;
    const int Kt = (ym + 1) * 128;  // keys needed by rows ym*128..+127
    floatx4 acc[4][2];
    mainloop(Ab, Bb, SEQ, SEQ, Kt, lsA, lsB,
             tid, wave, quad, l15, wm, wn, acc);

    float* Cf = O + (size_t)z * SEQ * DIM;
    const int m0 = ym * 128 + wm + quad * 4;
    const int n0 = blockIdx.x * 64 + wn + l15;
#pragma unroll
    for (int j = 0; j < 2; j++)
#pragma unroll
        for (int i = 0; i < 4; i++)
#pragma unroll
            for (int r = 0; r < 4; r++)
                Cf[(size_t)(m0 + i * 16 + r) * DIM + (n0 + j * 16)] = acc[i][j][r];
}

// -------- causal softmax: one row per block, register-resident, 1R+1W --------
__global__ __launch_bounds__(256) void softmax_causal(u16* __restrict__ S) {
    const int q = blockIdx.x, b = blockIdx.y, tid = threadIdx.x;
    u16* row = S + ((size_t)b * SEQ + q) * SEQ;
    const int L = q + 1;                    // valid keys
    const int Z = ((q >> 7) + 1) << 7;      // zero-fill bound = PV's K_eff
    const int k0 = tid * 8;
    __shared__ float redm[4], reds[4];

    uint4 rv = ((const uint4*)row)[tid];
    unsigned w[4] = {rv.x, rv.y, rv.z, rv.w};
    float f[8];
#pragma unroll
    for (int e = 0; e < 8; e++) {
        u16 h = (u16)((w[e >> 1] >> ((e & 1) * 16)) & 0xFFFFu);
        f[e] = (k0 + e < L) ? bf2f(h) : -3.0e38f;
    }
    float m = f[0];
#pragma unroll
    for (int e = 1; e < 8; e++) m = fmaxf(m, f[e]);
#pragma unroll
    for (int o = 32; o > 0; o >>= 1) m = fmaxf(m, __shfl_xor(m, o));
    if ((tid & 63) == 0) redm[tid >> 6] = m;
    __syncthreads();
    m = fmaxf(fmaxf(redm[0], redm[1]), fmaxf(redm[2], redm[3]));

    float p[8];
    float s = 0.f;
#pragma unroll
    for (int e = 0; e < 8; e++) {
        p[e] = (k0 + e < L) ? __expf(f[e] - m) : 0.f;
        s += p[e];
    }
#pragma unroll
    for (int o = 32; o > 0; o >>= 1) s += __shfl_xor(s, o);
    if ((tid & 63) == 0) reds[tid >> 6] = s;
    __syncthreads();
    s = reds[0] + reds[1] + reds[2] + reds[3];
    const float inv = 1.0f / s;

    if (k0 < Z) {
        unsigned o2[4];
#pragma unroll
        for (int e = 0; e < 4; e++) {
            unsigned lo = f2bf(p[2 * e] * inv);
            unsigned hi = f2bf(p[2 * e + 1] * inv);
            o2[e] = lo | (hi << 16);
        }
        uint4 ov = {o2[0], o2[1], o2[2], o2[3]};
        ((uint4*)row)[tid] = ov;
    }
}

extern "C" void kernel_launch(void* const* d_in, const int* in_sizes, int n_in,
                              void* d_out, int out_size, void* d_ws, size_t ws_size,
                              hipStream_t stream) {
    const float* x = (const float*)d_in[0];
    const float* Wq = (const float*)d_in[1];
    const float* bq = (const float*)d_in[2];
    const float* Wk = (const float*)d_in[3];
    const float* bk = (const float*)d_in[4];
    const float* Wv = (const float*)d_in[5];
    const float* bv = (const float*)d_in[6];
    float* out = (float*)d_out;

    char* ws = (char*)d_ws;
    const size_t MB = 1024ull * 1024ull;
    // layout: [0,32MB) early: xb(16MB)+Wt(6MB); late: S/P bf16 (32MB)
    //         [32,48) Q bf16 ; [48,64) K bf16 ; [64,80) Vt bf16 [d][s] per batch
    u16* S = (u16*)ws;
    u16* xb = (u16*)ws;
    u16* Wt = (u16*)(ws + 16 * MB);
    u16* QK = (u16*)(ws + 32 * MB);
    u16* Vt = (u16*)(ws + 64 * MB);
    const size_t MAT = (size_t)B_ * SEQ * DIM;  // 8M elements
    u16* Q = QK;
    u16* Km = QK + MAT;

    const float scale = 0.03125f;  // 1/sqrt(1024)

    convert_x<<<8192, 256, 0, stream>>>((const float4*)x, (ushort4*)xb);
    transpose_w<<<dim3(16, 16, 3), dim3(32, 8), 0, stream>>>(Wq, Wk, Wv, Wt);
    gemm_qkv<<<dim3(48, 64), 256, 0, stream>>>(xb, Wt, QK, bq, bk, bv, Vt);
    gemm_scores<<<dim3(32, 16, 4), 256, 0, stream>>>(Q, Km, S, scale);
    softmax_causal<<<dim3(SEQ, B_), 256, 0, stream>>>(S);
    gemm_pv<<<dim3(16, 16, 4), 256, 0, stream>>>(S, Vt, out);
}

// Round 6
// 282.565 us; speedup vs baseline: 1.0004x; 1.0004x over previous
//
#include <hip/hip_runtime.h>

typedef unsigned short u16;
typedef __bf16 bf16x8 __attribute__((ext_vector_type(8)));
typedef float floatx4 __attribute__((ext_vector_type(4)));

#define B_ 4
#define SEQ 2048
#define DIM 1024

__device__ __forceinline__ u16 f2bf(float f) {
    unsigned u = __builtin_bit_cast(unsigned, f);
    u += 0x7FFFu + ((u >> 16) & 1u);
    return (u16)(u >> 16);
}
__device__ __forceinline__ float bf2f(u16 h) {
    unsigned u = ((unsigned)h) << 16;
    return __builtin_bit_cast(float, u);
}

#define GPTR(p) ((const __attribute__((address_space(1))) void*)(p))
#define LPTR(p) ((__attribute__((address_space(3))) void*)(p))

// ---------------- convert x fp32 -> bf16 ----------------
__global__ __launch_bounds__(256) void convert_x(const float4* __restrict__ x,
                                                 ushort4* __restrict__ xb) {
    int i = blockIdx.x * 256 + threadIdx.x;  // 2M float4s
    float4 v = x[i];
    ushort4 o;
    o.x = f2bf(v.x); o.y = f2bf(v.y); o.z = f2bf(v.z); o.w = f2bf(v.w);
    xb[i] = o;
}

// ---------------- transpose W [k][n] fp32 -> Wt [n][k] bf16 ----------------
__global__ __launch_bounds__(256) void transpose_w(const float* __restrict__ Wq,
                                                   const float* __restrict__ Wk,
                                                   const float* __restrict__ Wv,
                                                   u16* __restrict__ Wt) {
    __shared__ u16 t[64][66];
    const int z = blockIdx.z;
    const float* W = (z == 0) ? Wq : ((z == 1) ? Wk : Wv);
    u16* out = Wt + (size_t)z * DIM * DIM;
    const int tx = threadIdx.x, ty = threadIdx.y;  // (32,8)
    const int k0 = blockIdx.x * 64, n0 = blockIdx.y * 64;
#pragma unroll
    for (int j = 0; j < 8; j++) {
        int k = ty + 8 * j;
        float2 v = *(const float2*)(W + (size_t)(k0 + k) * DIM + n0 + 2 * tx);
        t[2 * tx][k] = f2bf(v.x);
        t[2 * tx + 1][k] = f2bf(v.y);
    }
    __syncthreads();
#pragma unroll
    for (int j = 0; j < 8; j++) {
        int n = ty + 8 * j;
        ushort2 o;
        o.x = t[n][2 * tx];
        o.y = t[n][2 * tx + 1];
        *(ushort2*)(out + (size_t)(n0 + n) * DIM + k0 + 2 * tx) = o;
    }
}

// ---- 128x64 bf16 MFMA mainloop, BK=64 as two 32-col panels -----------------
// A [m][k] row-major, B transposed [n][k]. 4 waves in 2x2; wave = 64mx32n.
// LDS layout bank-swizzled: within each 16-row group, segment (l, ks) lives
// at slot l*4 + (ks ^ ((l>>1)&3)).  Write side picks the matching global
// k-segment per lane; read side XORs quad. 16-lane read groups then hit all
// 8 bank-groups exactly 2x (2-way = free, m136). Kills the 8/bank conflict
// of plain row-major (was 9.6M SQ_LDS_BANK_CONFLICT, ~4x ds_read stretch).
__device__ __forceinline__ void mainloop(
    const u16* __restrict__ Ab, const u16* __restrict__ Bb, int lda, int ldb,
    int Kt, u16* lsA, u16* lsB, int tid, int wave, int quad, int l15,
    int wm, int wn, floatx4 (&acc)[4][2]) {
    const int srow = tid >> 2;                                // 0..63
    const int scol = ((tid & 3) ^ ((tid >> 3) & 3)) * 8;      // swizzled kseg
    const u16* gA = Ab + (size_t)srow * lda + scol;
    const u16* gB = Bb + (size_t)srow * ldb + scol;
    const int swq = (quad ^ ((l15 >> 1) & 3)) * 8;            // read-side xor
    const int rowA = l15 * 32;                                // l15*4 slots

#pragma unroll
    for (int i = 0; i < 4; i++)
#pragma unroll
        for (int j = 0; j < 2; j++) {
            floatx4 zz = {0.f, 0.f, 0.f, 0.f};
            acc[i][j] = zz;
        }

    for (int k0 = 0; k0 < Kt; k0 += 64) {
#pragma unroll
        for (int h = 0; h < 2; h++) {
            __builtin_amdgcn_global_load_lds(GPTR(gA + h * 32),
                LPTR(lsA + h * 4096 + wave * 512), 16, 0, 0);
            __builtin_amdgcn_global_load_lds(GPTR(gA + (size_t)64 * lda + h * 32),
                LPTR(lsA + h * 4096 + 2048 + wave * 512), 16, 0, 0);
            __builtin_amdgcn_global_load_lds(GPTR(gB + h * 32),
                LPTR(lsB + h * 2048 + wave * 512), 16, 0, 0);
        }
        gA += 64; gB += 64;
        __syncthreads();

#pragma unroll
        for (int h = 0; h < 2; h++) {
            bf16x8 af[4], bfr[2];
#pragma unroll
            for (int i = 0; i < 4; i++)
                af[i] = *(const bf16x8*)(lsA + h * 4096 + (wm + i * 16) * 32 + rowA + swq);
#pragma unroll
            for (int j = 0; j < 2; j++)
                bfr[j] = *(const bf16x8*)(lsB + h * 2048 + (wn + j * 16) * 32 + rowA + swq);
#pragma unroll
            for (int i = 0; i < 4; i++)
#pragma unroll
                for (int j = 0; j < 2; j++)
                    acc[i][j] = __builtin_amdgcn_mfma_f32_16x16x32_bf16(af[i], bfr[j], acc[i][j], 0, 0, 0);
        }
        __syncthreads();
    }
}

// ---------------- QKV projection: C = xb @ Wt^T + bias ----------------------
// grid (48,64): z = x>>4 (Q,K,V), 64-col tile = x&15. x-adjacent share A-tile.
__global__ __launch_bounds__(256, 4) void gemm_qkv(
    const u16* __restrict__ A, const u16* __restrict__ Bt, u16* __restrict__ QK,
    const float* __restrict__ b0, const float* __restrict__ b1, const float* __restrict__ b2,
    u16* __restrict__ VtOut) {
    __shared__ union {
        struct { u16 a[128 * 64]; u16 b[64 * 64]; } stage;  // 24 KB
        u16 epT[64 * 136];       // V^T epilogue staging (17.4 KB)
    } sm;
    const int tid = threadIdx.x;
    const int wave = tid >> 6, lane = tid & 63;
    const int quad = lane >> 4, l15 = lane & 15;
    const int wm = (wave >> 1) * 64, wn = (wave & 1) * 32;
    const int z = blockIdx.x >> 4, xn = blockIdx.x & 15, yb = blockIdx.y;

    const u16* Ab = A + (size_t)yb * 128 * DIM;
    const u16* Bb = Bt + (size_t)z * DIM * DIM + (size_t)xn * 64 * DIM;
    floatx4 acc[4][2];
    mainloop(Ab, Bb, DIM, DIM, DIM, sm.stage.a, sm.stage.b,
             tid, wave, quad, l15, wm, wn, acc);

    const int colbase = xn * 64;
    const int mq = quad * 4;
    const float* bias = (z == 0) ? b0 : ((z == 1) ? b1 : b2);
    const int n0 = colbase + wn + l15;

    if (z < 2) {
        u16* Cb = QK + (size_t)z * B_ * SEQ * DIM;
        const int m0 = yb * 128 + wm + mq;
#pragma unroll
        for (int j = 0; j < 2; j++) {
            float bv_ = bias[n0 + j * 16];
#pragma unroll
            for (int i = 0; i < 4; i++)
#pragma unroll
                for (int r = 0; r < 4; r++)
                    Cb[(size_t)(m0 + i * 16 + r) * DIM + (n0 + j * 16)] = f2bf(acc[i][j][r] + bv_);
        }
        return;
    }

    // z == 2: write V^T [d][s] per batch via LDS transpose staging (one pass)
    float addj[2];
#pragma unroll
    for (int j = 0; j < 2; j++) addj[j] = bias[n0 + j * 16];
    __syncthreads();
#pragma unroll
    for (int i = 0; i < 4; i++)
#pragma unroll
        for (int j = 0; j < 2; j++)
#pragma unroll
            for (int r = 0; r < 4; r++) {
                int lr = wm + i * 16 + mq + r;   // local row 0..127 (token)
                int lc = wn + j * 16 + l15;      // local col 0..63  (dim)
                sm.epT[lc * 136 + lr] = f2bf(acc[i][j][r] + addj[j]);
            }
    __syncthreads();
    const int b = (yb * 128) >> 11;
    const int sb = (yb * 128) & (SEQ - 1);
    u16* Vb = VtOut + (size_t)b * DIM * SEQ;
#pragma unroll
    for (int k = 0; k < 4; k++) {
        int s2 = tid + 256 * k;        // 0..1023
        int n = s2 >> 4, seg = s2 & 15;
        uint4 val = *(const uint4*)&sm.epT[n * 136 + seg * 8];
        *(uint4*)(Vb + (size_t)(colbase + n) * SEQ + sb + seg * 8) = val;
    }
}

// ------- scores: S = Q @ K^T * scale (128x64, causal, heavy-first) ----------
__global__ __launch_bounds__(256, 4) void gemm_scores(
    const u16* __restrict__ Q, const u16* __restrict__ K, u16* __restrict__ S,
    float scale) {
    const int ym = gridDim.y - 1 - blockIdx.y;   // 0..15, heavy-first
    if ((int)blockIdx.x > 2 * ym + 1) return;    // fully-masked 64-col tile

    __shared__ u16 lsA[128 * 64];   // 16 KB
    __shared__ u16 lsB[64 * 64];    // 8 KB
    const int tid = threadIdx.x;
    const int wave = tid >> 6, lane = tid & 63;
    const int quad = lane >> 4, l15 = lane & 15;
    const int wm = (wave >> 1) * 64, wn = (wave & 1) * 32;
    const int z = blockIdx.z;

    const u16* Ab = Q + (size_t)z * SEQ * DIM + (size_t)ym * 128 * DIM;
    const u16* Bb = K + (size_t)z * SEQ * DIM + (size_t)blockIdx.x * 64 * DIM;
    floatx4 acc[4][2];
    mainloop(Ab, Bb, DIM, DIM, DIM, lsA, lsB,
             tid, wave, quad, l15, wm, wn, acc);

    u16* Cb = S + (size_t)z * SEQ * SEQ;
    const int m0 = ym * 128 + wm + quad * 4;
    const int n0 = blockIdx.x * 64 + wn + l15;
#pragma unroll
    for (int j = 0; j < 2; j++)
#pragma unroll
        for (int i = 0; i < 4; i++)
#pragma unroll
            for (int r = 0; r < 4; r++)
                Cb[(size_t)(m0 + i * 16 + r) * SEQ + (n0 + j * 16)] = f2bf(acc[i][j][r] * scale);
}

// ------- context: out = P @ Vt^T (128x64, K limited, heavy-first) -----------
__global__ __launch_bounds__(256, 4) void gemm_pv(
    const u16* __restrict__ P, const u16* __restrict__ Vt, float* __restrict__ O) {
    const int ym = gridDim.y - 1 - blockIdx.y;   // 0..15, heavy-first
    __shared__ u16 lsA[128 * 64];
    __shared__ u16 lsB[64 * 64];
    const int tid = threadIdx.x;
    const int wave = tid >> 6, lane = tid & 63;
    const int quad = lane >> 4, l15 = lane & 15;
    const int wm = (wave >> 1) * 64, wn = (wave & 1) * 32;
    const int z = blockIdx.z;

    const u16* Ab = P + (size_t)z * SEQ * SEQ + (size_t)ym * 128 * SEQ;
    const u16* Bb = Vt + (size_t)z * DIM * SEQ + (size_t)blockIdx.x * 64 * SEQ;
    const int Kt = (ym + 1) * 128;  // keys needed by rows ym*128..+127
    floatx4 acc[4][2];
    mainloop(Ab, Bb, SEQ, SEQ, Kt, lsA, lsB,
             tid, wave, quad, l15, wm, wn, acc);

    float* Cf = O + (size_t)z * SEQ * DIM;
    const int m0 = ym * 128 + wm + quad * 4;
    const int n0 = blockIdx.x * 64 + wn + l15;
#pragma unroll
    for (int j = 0; j < 2; j++)
#pragma unroll
        for (int i = 0; i < 4; i++)
#pragma unroll
            for (int r = 0; r < 4; r++)
                Cf[(size_t)(m0 + i * 16 + r) * DIM + (n0 + j * 16)] = acc[i][j][r];
}

// -------- causal softmax: one row per block, register-resident, 1R+1W --------
__global__ __launch_bounds__(256) void softmax_causal(u16* __restrict__ S) {
    const int q = blockIdx.x, b = blockIdx.y, tid = threadIdx.x;
    u16* row = S + ((size_t)b * SEQ + q) * SEQ;
    const int L = q + 1;                    // valid keys
    const int Z = ((q >> 7) + 1) << 7;      // zero-fill bound = PV's K_eff
    const int k0 = tid * 8;
    __shared__ float redm[4], reds[4];

    uint4 rv = ((const uint4*)row)[tid];
    unsigned w[4] = {rv.x, rv.y, rv.z, rv.w};
    float f[8];
#pragma unroll
    for (int e = 0; e < 8; e++) {
        u16 h = (u16)((w[e >> 1] >> ((e & 1) * 16)) & 0xFFFFu);
        f[e] = (k0 + e < L) ? bf2f(h) : -3.0e38f;
    }
    float m = f[0];
#pragma unroll
    for (int e = 1; e < 8; e++) m = fmaxf(m, f[e]);
#pragma unroll
    for (int o = 32; o > 0; o >>= 1) m = fmaxf(m, __shfl_xor(m, o));
    if ((tid & 63) == 0) redm[tid >> 6] = m;
    __syncthreads();
    m = fmaxf(fmaxf(redm[0], redm[1]), fmaxf(redm[2], redm[3]));

    float p[8];
    float s = 0.f;
#pragma unroll
    for (int e = 0; e < 8; e++) {
        p[e] = (k0 + e < L) ? __expf(f[e] - m) : 0.f;
        s += p[e];
    }
#pragma unroll
    for (int o = 32; o > 0; o >>= 1) s += __shfl_xor(s, o);
    if ((tid & 63) == 0) reds[tid >> 6] = s;
    __syncthreads();
    s = reds[0] + reds[1] + reds[2] + reds[3];
    const float inv = 1.0f / s;

    if (k0 < Z) {
        unsigned o2[4];
#pragma unroll
        for (int e = 0; e < 4; e++) {
            unsigned lo = f2bf(p[2 * e] * inv);
            unsigned hi = f2bf(p[2 * e + 1] * inv);
            o2[e] = lo | (hi << 16);
        }
        uint4 ov = {o2[0], o2[1], o2[2], o2[3]};
        ((uint4*)row)[tid] = ov;
    }
}

extern "C" void kernel_launch(void* const* d_in, const int* in_sizes, int n_in,
                              void* d_out, int out_size, void* d_ws, size_t ws_size,
                              hipStream_t stream) {
    const float* x = (const float*)d_in[0];
    const float* Wq = (const float*)d_in[1];
    const float* bq = (const float*)d_in[2];
    const float* Wk = (const float*)d_in[3];
    const float* bk = (const float*)d_in[4];
    const float* Wv = (const float*)d_in[5];
    const float* bv = (const float*)d_in[6];
    float* out = (float*)d_out;

    char* ws = (char*)d_ws;
    const size_t MB = 1024ull * 1024ull;
    // layout: [0,32MB) early: xb(16MB)+Wt(6MB); late: S/P bf16 (32MB)
    //         [32,48) Q bf16 ; [48,64) K bf16 ; [64,80) Vt bf16 [d][s] per batch
    u16* S = (u16*)ws;
    u16* xb = (u16*)ws;
    u16* Wt = (u16*)(ws + 16 * MB);
    u16* QK = (u16*)(ws + 32 * MB);
    u16* Vt = (u16*)(ws + 64 * MB);
    const size_t MAT = (size_t)B_ * SEQ * DIM;  // 8M elements
    u16* Q = QK;
    u16* Km = QK + MAT;

    const float scale = 0.03125f;  // 1/sqrt(1024)

    convert_x<<<8192, 256, 0, stream>>>((const float4*)x, (ushort4*)xb);
    transpose_w<<<dim3(16, 16, 3), dim3(32, 8), 0, stream>>>(Wq, Wk, Wv, Wt);
    gemm_qkv<<<dim3(48, 64), 256, 0, stream>>>(xb, Wt, QK, bq, bk, bv, Vt);
    gemm_scores<<<dim3(32, 16, 4), 256, 0, stream>>>(Q, Km, S, scale);
    softmax_causal<<<dim3(SEQ, B_), 256, 0, stream>>>(S);
    gemm_pv<<<dim3(16, 16, 4), 256, 0, stream>>>(S, Vt, out);
}

// Round 7
// 249.569 us; speedup vs baseline: 1.1326x; 1.1322x over previous
//
#include <hip/hip_runtime.h>

typedef unsigned short u16;
typedef __bf16 bf16x8 __attribute__((ext_vector_type(8)));
typedef float floatx4 __attribute__((ext_vector_type(4)));

#define B_ 4
#define SEQ 2048
#define DIM 1024

__device__ __forceinline__ u16 f2bf(float f) {
    unsigned u = __builtin_bit_cast(unsigned, f);
    u += 0x7FFFu + ((u >> 16) & 1u);
    return (u16)(u >> 16);
}
__device__ __forceinline__ float bf2f(u16 h) {
    unsigned u = ((unsigned)h) << 16;
    return __builtin_bit_cast(float, u);
}

#define GPTR(p) ((const __attribute__((address_space(1))) void*)(p))
#define LPTR(p) ((__attribute__((address_space(3))) void*)(p))

// ---------------- convert x fp32 -> bf16 ----------------
__global__ __launch_bounds__(256) void convert_x(const float4* __restrict__ x,
                                                 ushort4* __restrict__ xb) {
    int i = blockIdx.x * 256 + threadIdx.x;  // 2M float4s
    float4 v = x[i];
    ushort4 o;
    o.x = f2bf(v.x); o.y = f2bf(v.y); o.z = f2bf(v.z); o.w = f2bf(v.w);
    xb[i] = o;
}

// ---------------- transpose W [k][n] fp32 -> Wt [n][k] bf16 ----------------
__global__ __launch_bounds__(256) void transpose_w(const float* __restrict__ Wq,
                                                   const float* __restrict__ Wk,
                                                   const float* __restrict__ Wv,
                                                   u16* __restrict__ Wt) {
    __shared__ u16 t[64][66];
    const int z = blockIdx.z;
    const float* W = (z == 0) ? Wq : ((z == 1) ? Wk : Wv);
    u16* out = Wt + (size_t)z * DIM * DIM;
    const int tx = threadIdx.x, ty = threadIdx.y;  // (32,8)
    const int k0 = blockIdx.x * 64, n0 = blockIdx.y * 64;
#pragma unroll
    for (int j = 0; j < 8; j++) {
        int k = ty + 8 * j;
        float2 v = *(const float2*)(W + (size_t)(k0 + k) * DIM + n0 + 2 * tx);
        t[2 * tx][k] = f2bf(v.x);
        t[2 * tx + 1][k] = f2bf(v.y);
    }
    __syncthreads();
#pragma unroll
    for (int j = 0; j < 8; j++) {
        int n = ty + 8 * j;
        ushort2 o;
        o.x = t[n][2 * tx];
        o.y = t[n][2 * tx + 1];
        *(ushort2*)(out + (size_t)(n0 + n) * DIM + k0 + 2 * tx) = o;
    }
}

// ---- 128x128 bf16 MFMA mainloop, BK=64, 4 waves of 64x64 -------------------
// A [m][k] row-major, B transposed [n][k]. Swizzled LDS (R6-proven, 196K
// conflicts): seg (l,ks) at slot l*4 + (ks ^ ((l>>1)&3)); read XORs quad.
// LDS traffic/iter: 32 KB write + 64 KB read = 750 cyc vs 515 cyc MFMA ->
// 69% ceiling (was 46% at 64x32/wave).
__device__ __forceinline__ void mainloop(
    const u16* __restrict__ Ab, const u16* __restrict__ Bb, int lda, int ldb,
    int Kt, u16* lsA, u16* lsB, int tid, int wave, int quad, int l15,
    int wm, int wn, floatx4 (&acc)[4][4]) {
    const int srow = tid >> 2;                                // 0..63
    const int scol = ((tid & 3) ^ ((tid >> 3) & 3)) * 8;      // swizzled kseg
    const u16* gA = Ab + (size_t)srow * lda + scol;
    const u16* gB = Bb + (size_t)srow * ldb + scol;
    const int swq = (quad ^ ((l15 >> 1) & 3)) * 8;            // read-side xor

#pragma unroll
    for (int i = 0; i < 4; i++)
#pragma unroll
        for (int j = 0; j < 4; j++) {
            floatx4 zz = {0.f, 0.f, 0.f, 0.f};
            acc[i][j] = zz;
        }

    for (int k0 = 0; k0 < Kt; k0 += 64) {
#pragma unroll
        for (int h = 0; h < 2; h++)
#pragma unroll
            for (int c = 0; c < 2; c++) {
                __builtin_amdgcn_global_load_lds(
                    GPTR(gA + (size_t)c * 64 * lda + h * 32),
                    LPTR(lsA + h * 4096 + c * 2048 + wave * 512), 16, 0, 0);
                __builtin_amdgcn_global_load_lds(
                    GPTR(gB + (size_t)c * 64 * ldb + h * 32),
                    LPTR(lsB + h * 4096 + c * 2048 + wave * 512), 16, 0, 0);
            }
        gA += 64; gB += 64;
        __syncthreads();

#pragma unroll
        for (int h = 0; h < 2; h++) {
            bf16x8 af[4];
#pragma unroll
            for (int i = 0; i < 4; i++)
                af[i] = *(const bf16x8*)(lsA + h * 4096 + (wm + i * 16 + l15) * 32 + swq);
#pragma unroll
            for (int j = 0; j < 4; j++) {
                bf16x8 bfr = *(const bf16x8*)(lsB + h * 4096 + (wn + j * 16 + l15) * 32 + swq);
#pragma unroll
                for (int i = 0; i < 4; i++)
                    acc[i][j] = __builtin_amdgcn_mfma_f32_16x16x32_bf16(af[i], bfr, acc[i][j], 0, 0, 0);
            }
        }
        __syncthreads();
    }
}

// ---------------- QKV projection: C = xb @ Wt^T + bias ----------------------
// grid (24,64): z = x>>3 (Q,K,V), 128-col tile = x&7. x-adjacent share A-tile.
__global__ __launch_bounds__(256, 3) void gemm_qkv(
    const u16* __restrict__ A, const u16* __restrict__ Bt, u16* __restrict__ QK,
    const float* __restrict__ b0, const float* __restrict__ b1, const float* __restrict__ b2,
    u16* __restrict__ VtOut) {
    __shared__ union {
        struct { u16 a[128 * 64]; u16 b[128 * 64]; } stage;  // 32 KB
        u16 epT[64 * 136];       // V^T epilogue staging (17.4 KB)
    } sm;
    const int tid = threadIdx.x;
    const int wave = tid >> 6, lane = tid & 63;
    const int quad = lane >> 4, l15 = lane & 15;
    const int wm = (wave >> 1) * 64, wn = (wave & 1) * 64;
    const int z = blockIdx.x >> 3, xn = blockIdx.x & 7, yb = blockIdx.y;

    const u16* Ab = A + (size_t)yb * 128 * DIM;
    const u16* Bb = Bt + (size_t)z * DIM * DIM + (size_t)xn * 128 * DIM;
    floatx4 acc[4][4];
    mainloop(Ab, Bb, DIM, DIM, DIM, sm.stage.a, sm.stage.b,
             tid, wave, quad, l15, wm, wn, acc);

    const int colbase = xn * 128;
    const int mq = quad * 4;
    const float* bias = (z == 0) ? b0 : ((z == 1) ? b1 : b2);
    const int n0 = colbase + wn + l15;

    if (z < 2) {
        u16* Cb = QK + (size_t)z * B_ * SEQ * DIM;
        const int m0 = yb * 128 + wm + mq;
#pragma unroll
        for (int j = 0; j < 4; j++) {
            float bv_ = bias[n0 + j * 16];
#pragma unroll
            for (int i = 0; i < 4; i++)
#pragma unroll
                for (int r = 0; r < 4; r++)
                    Cb[(size_t)(m0 + i * 16 + r) * DIM + (n0 + j * 16)] = f2bf(acc[i][j][r] + bv_);
        }
        return;
    }

    // z == 2: write V^T [d][s] per batch via LDS transpose staging.
    // Two chunks of 64 dims; chunk c holds dims c*64..c*64+63 (waves wn==c*64),
    // tokens 0..127 (wave m-halves).
    float addj[4];
#pragma unroll
    for (int j = 0; j < 4; j++) addj[j] = bias[n0 + j * 16];
    const int b = (yb * 128) >> 11;
    const int sb = (yb * 128) & (SEQ - 1);
    u16* Vb = VtOut + (size_t)b * DIM * SEQ;
#pragma unroll
    for (int c = 0; c < 2; c++) {
        __syncthreads();
        if ((wave & 1) == c) {
#pragma unroll
            for (int i = 0; i < 4; i++)
#pragma unroll
                for (int j = 0; j < 4; j++)
#pragma unroll
                    for (int r = 0; r < 4; r++) {
                        int lr = wm + i * 16 + mq + r;   // token 0..127
                        int lc = j * 16 + l15;           // dim-in-chunk 0..63
                        sm.epT[lc * 136 + lr] = f2bf(acc[i][j][r] + addj[j]);
                    }
        }
        __syncthreads();
#pragma unroll
        for (int k = 0; k < 4; k++) {
            int s2 = tid + 256 * k;        // 0..1023
            int n = s2 >> 4, seg = s2 & 15;
            uint4 val = *(const uint4*)&sm.epT[n * 136 + seg * 8];
            *(uint4*)(Vb + (size_t)(colbase + c * 64 + n) * SEQ + sb + seg * 8) = val;
        }
    }
}

// ------- scores: S = Q @ K^T * scale (128x128, causal, heavy-first) ---------
__global__ __launch_bounds__(256, 3) void gemm_scores(
    const u16* __restrict__ Q, const u16* __restrict__ K, u16* __restrict__ S,
    float scale) {
    const int ym = gridDim.y - 1 - blockIdx.y;   // 0..15, heavy-first
    if ((int)blockIdx.x > ym) return;            // fully-masked tile

    __shared__ u16 lsA[128 * 64];   // 16 KB
    __shared__ u16 lsB[128 * 64];   // 16 KB
    const int tid = threadIdx.x;
    const int wave = tid >> 6, lane = tid & 63;
    const int quad = lane >> 4, l15 = lane & 15;
    const int wm = (wave >> 1) * 64, wn = (wave & 1) * 64;
    const int z = blockIdx.z;

    const u16* Ab = Q + (size_t)z * SEQ * DIM + (size_t)ym * 128 * DIM;
    const u16* Bb = K + (size_t)z * SEQ * DIM + (size_t)blockIdx.x * 128 * DIM;
    floatx4 acc[4][4];
    mainloop(Ab, Bb, DIM, DIM, DIM, lsA, lsB,
             tid, wave, quad, l15, wm, wn, acc);

    u16* Cb = S + (size_t)z * SEQ * SEQ;
    const int m0 = ym * 128 + wm + quad * 4;
    const int n0 = blockIdx.x * 128 + wn + l15;
#pragma unroll
    for (int j = 0; j < 4; j++)
#pragma unroll
        for (int i = 0; i < 4; i++)
#pragma unroll
            for (int r = 0; r < 4; r++)
                Cb[(size_t)(m0 + i * 16 + r) * SEQ + (n0 + j * 16)] = f2bf(acc[i][j][r] * scale);
}

// ------- context: out = P @ Vt^T (128x128, K limited, heavy-first) ----------
__global__ __launch_bounds__(256, 3) void gemm_pv(
    const u16* __restrict__ P, const u16* __restrict__ Vt, float* __restrict__ O) {
    const int ym = gridDim.y - 1 - blockIdx.y;   // 0..15, heavy-first
    __shared__ u16 lsA[128 * 64];
    __shared__ u16 lsB[128 * 64];
    const int tid = threadIdx.x;
    const int wave = tid >> 6, lane = tid & 63;
    const int quad = lane >> 4, l15 = lane & 15;
    const int wm = (wave >> 1) * 64, wn = (wave & 1) * 64;
    const int z = blockIdx.z;

    const u16* Ab = P + (size_t)z * SEQ * SEQ + (size_t)ym * 128 * SEQ;
    const u16* Bb = Vt + (size_t)z * DIM * SEQ + (size_t)blockIdx.x * 128 * SEQ;
    const int Kt = (ym + 1) * 128;  // keys needed by rows ym*128..+127
    floatx4 acc[4][4];
    mainloop(Ab, Bb, SEQ, SEQ, Kt, lsA, lsB,
             tid, wave, quad, l15, wm, wn, acc);

    float* Cf = O + (size_t)z * SEQ * DIM;
    const int m0 = ym * 128 + wm + quad * 4;
    const int n0 = blockIdx.x * 128 + wn + l15;
#pragma unroll
    for (int j = 0; j < 4; j++)
#pragma unroll
        for (int i = 0; i < 4; i++)
#pragma unroll
            for (int r = 0; r < 4; r++)
                Cf[(size_t)(m0 + i * 16 + r) * DIM + (n0 + j * 16)] = acc[i][j][r];
}

// -------- causal softmax: one row per block, register-resident, 1R+1W --------
__global__ __launch_bounds__(256) void softmax_causal(u16* __restrict__ S) {
    const int q = blockIdx.x, b = blockIdx.y, tid = threadIdx.x;
    u16* row = S + ((size_t)b * SEQ + q) * SEQ;
    const int L = q + 1;                    // valid keys
    const int Z = ((q >> 7) + 1) << 7;      // zero-fill bound = PV's K_eff
    const int k0 = tid * 8;
    __shared__ float redm[4], reds[4];

    uint4 rv = ((const uint4*)row)[tid];
    unsigned w[4] = {rv.x, rv.y, rv.z, rv.w};
    float f[8];
#pragma unroll
    for (int e = 0; e < 8; e++) {
        u16 h = (u16)((w[e >> 1] >> ((e & 1) * 16)) & 0xFFFFu);
        f[e] = (k0 + e < L) ? bf2f(h) : -3.0e38f;
    }
    float m = f[0];
#pragma unroll
    for (int e = 1; e < 8; e++) m = fmaxf(m, f[e]);
#pragma unroll
    for (int o = 32; o > 0; o >>= 1) m = fmaxf(m, __shfl_xor(m, o));
    if ((tid & 63) == 0) redm[tid >> 6] = m;
    __syncthreads();
    m = fmaxf(fmaxf(redm[0], redm[1]), fmaxf(redm[2], redm[3]));

    float p[8];
    float s = 0.f;
#pragma unroll
    for (int e = 0; e < 8; e++) {
        p[e] = (k0 + e < L) ? __expf(f[e] - m) : 0.f;
        s += p[e];
    }
#pragma unroll
    for (int o = 32; o > 0; o >>= 1) s += __shfl_xor(s, o);
    if ((tid & 63) == 0) reds[tid >> 6] = s;
    __syncthreads();
    s = reds[0] + reds[1] + reds[2] + reds[3];
    const float inv = 1.0f / s;

    if (k0 < Z) {
        unsigned o2[4];
#pragma unroll
        for (int e = 0; e < 4; e++) {
            unsigned lo = f2bf(p[2 * e] * inv);
            unsigned hi = f2bf(p[2 * e + 1] * inv);
            o2[e] = lo | (hi << 16);
        }
        uint4 ov = {o2[0], o2[1], o2[2], o2[3]};
        ((uint4*)row)[tid] = ov;
    }
}

extern "C" void kernel_launch(void* const* d_in, const int* in_sizes, int n_in,
                              void* d_out, int out_size, void* d_ws, size_t ws_size,
                              hipStream_t stream) {
    const float* x = (const float*)d_in[0];
    const float* Wq = (const float*)d_in[1];
    const float* bq = (const float*)d_in[2];
    const float* Wk = (const float*)d_in[3];
    const float* bk = (const float*)d_in[4];
    const float* Wv = (const float*)d_in[5];
    const float* bv = (const float*)d_in[6];
    float* out = (float*)d_out;

    char* ws = (char*)d_ws;
    const size_t MB = 1024ull * 1024ull;
    // layout: [0,32MB) early: xb(16MB)+Wt(6MB); late: S/P bf16 (32MB)
    //         [32,48) Q bf16 ; [48,64) K bf16 ; [64,80) Vt bf16 [d][s] per batch
    u16* S = (u16*)ws;
    u16* xb = (u16*)ws;
    u16* Wt = (u16*)(ws + 16 * MB);
    u16* QK = (u16*)(ws + 32 * MB);
    u16* Vt = (u16*)(ws + 64 * MB);
    const size_t MAT = (size_t)B_ * SEQ * DIM;  // 8M elements
    u16* Q = QK;
    u16* Km = QK + MAT;

    const float scale = 0.03125f;  // 1/sqrt(1024)

    convert_x<<<8192, 256, 0, stream>>>((const float4*)x, (ushort4*)xb);
    transpose_w<<<dim3(16, 16, 3), dim3(32, 8), 0, stream>>>(Wq, Wk, Wv, Wt);
    gemm_qkv<<<dim3(24, 64), 256, 0, stream>>>(xb, Wt, QK, bq, bk, bv, Vt);
    gemm_scores<<<dim3(16, 16, 4), 256, 0, stream>>>(Q, Km, S, scale);
    softmax_causal<<<dim3(SEQ, B_), 256, 0, stream>>>(S);
    gemm_pv<<<dim3(8, 16, 4), 256, 0, stream>>>(S, Vt, out);
}